// Round 2
// baseline (1744.659 us; speedup 1.0000x reference)
//
#include <hip/hip_runtime.h>
#include <hip/hip_bf16.h>
#include <cstdint>
#include <cstddef>

typedef __bf16 bf16_t;
typedef __bf16 bf16x8 __attribute__((ext_vector_type(8)));
typedef __bf16 bf16x4 __attribute__((ext_vector_type(4)));
typedef float f32x4 __attribute__((ext_vector_type(4)));

// ---------------------------------------------------------------------------
// async global->LDS, 16B per lane. LDS dest is wave-uniform base + lane*16.
// ---------------------------------------------------------------------------
__device__ __forceinline__ void async16(const void* g, void* l) {
  __builtin_amdgcn_global_load_lds(
      (const __attribute__((address_space(1))) void*)g,
      (__attribute__((address_space(3))) void*)l,
      16, 0, 0);
}

// ---------------------------------------------------------------------------
// fp32 -> bf16 weight conversion (512x512 = 65536 float4, grid 256x256)
// ---------------------------------------------------------------------------
__global__ __launch_bounds__(256) void f2b(const float* __restrict__ in,
                                           bf16_t* __restrict__ out) {
  const int i = blockIdx.x * 256 + threadIdx.x;
  float4 v = ((const float4*)in)[i];
  bf16x4 o = { (__bf16)v.x, (__bf16)v.y, (__bf16)v.z, (__bf16)v.w };
  ((bf16x4*)out)[i] = o;
}

// ---------------------------------------------------------------------------
// GroupNorm for ONE batch b: x (C=512, N=4096) fp32 -> hb (N, C) bf16
// (transposed so downstream GEMMs are A@B^T, K-contiguous).
// 32 groups of 16 channels; one block per group; 256 threads.
// ---------------------------------------------------------------------------
__global__ __launch_bounds__(256) void groupnorm_t(const float* __restrict__ x,
                                                   const float* __restrict__ gamma,
                                                   const float* __restrict__ beta,
                                                   bf16_t* __restrict__ hb,
                                                   int b) {
  const int g = blockIdx.x;
  const int t = threadIdx.x;
  const float* xg = x + ((size_t)(b * 512 + g * 16)) * 4096;
  const float4* x4 = (const float4*)xg;

  float s = 0.f, ss = 0.f;
  #pragma unroll 8
  for (int i = t; i < 16384; i += 256) {
    float4 v = x4[i];
    s  += (v.x + v.y) + (v.z + v.w);
    ss += (v.x * v.x + v.y * v.y) + (v.z * v.z + v.w * v.w);
  }
  #pragma unroll
  for (int o = 32; o; o >>= 1) { s += __shfl_xor(s, o); ss += __shfl_xor(ss, o); }
  __shared__ float rs[4], rss[4];
  if ((t & 63) == 0) { rs[t >> 6] = s; rss[t >> 6] = ss; }
  __syncthreads();
  const float S  = (rs[0] + rs[1]) + (rs[2] + rs[3]);
  const float SS = (rss[0] + rss[1]) + (rss[2] + rss[3]);
  const float inv_n = 1.0f / 65536.0f;
  const float mean = S * inv_n;
  const float var  = SS * inv_n - mean * mean;
  const float rstd = rsqrtf(var + 1e-5f);

  float ga[16], be[16];
  #pragma unroll
  for (int cc = 0; cc < 16; cc++) {
    const float gm = gamma[g * 16 + cc] * rstd;
    ga[cc] = gm;
    be[cc] = beta[g * 16 + cc] - mean * gm;
  }

  bf16_t* hg = hb + g * 16;
  for (int n = t; n < 4096; n += 256) {
    bf16_t o[16];
    #pragma unroll
    for (int cc = 0; cc < 16; cc++)
      o[cc] = (bf16_t)(xg[(size_t)cc * 4096 + n] * ga[cc] + be[cc]);
    bf16x8* dst = (bf16x8*)(hg + (size_t)n * 512);
    dst[0] = *(bf16x8*)&o[0];
    dst[1] = *(bf16x8*)&o[8];
  }
}

// ---------------------------------------------------------------------------
// In-place row softmax on 4096-wide bf16 rows (scores -> probabilities).
// One block per row; each thread owns 16 contiguous values in registers.
// ---------------------------------------------------------------------------
__global__ __launch_bounds__(256) void softmax_row_bf16(bf16_t* __restrict__ SP) {
  const int row = blockIdx.x;
  const int t = threadIdx.x;
  bf16x8* R = (bf16x8*)(SP + (size_t)row * 4096) + t * 2;

  float v[16];
  bf16x8 a = R[0], b = R[1];
  #pragma unroll
  for (int i = 0; i < 8; i++) { v[i] = (float)a[i]; v[8 + i] = (float)b[i]; }

  float m = -3.0e38f;
  #pragma unroll
  for (int i = 0; i < 16; i++) m = fmaxf(m, v[i]);
  #pragma unroll
  for (int o = 32; o; o >>= 1) m = fmaxf(m, __shfl_xor(m, o));
  __shared__ float rm[4], rsum[4];
  if ((t & 63) == 0) rm[t >> 6] = m;
  __syncthreads();
  m = fmaxf(fmaxf(rm[0], rm[1]), fmaxf(rm[2], rm[3]));

  float s = 0.f;
  #pragma unroll
  for (int i = 0; i < 16; i++) { v[i] = __expf(v[i] - m); s += v[i]; }
  #pragma unroll
  for (int o = 32; o; o >>= 1) s += __shfl_xor(s, o);
  if ((t & 63) == 0) rsum[t >> 6] = s;
  __syncthreads();
  s = (rsum[0] + rsum[1]) + (rsum[2] + rsum[3]);
  const float inv = 1.0f / s;

  #pragma unroll
  for (int i = 0; i < 8; i++) { a[i] = (__bf16)(v[i] * inv); b[i] = (__bf16)(v[8 + i] * inv); }
  R[0] = a; R[1] = b;
}

// ---------------------------------------------------------------------------
// C = A @ B^T  (A: MxK row-major, B: NxK row-major, both bf16 K-contiguous).
// m97 structure: 128x128 tile, BK=32, 4 waves x (4x4) 16x16x32 bf16 MFMA,
// global_load_lds width=16 staging (wave-uniform LDS base + lane*16).
// C/D layout (verified m89/m91): col = lane&15, row = (lane>>4)*4 + reg.
// A/B operand: elem[m|n = lane&15][k = (lane>>4)*8 + j].
// BIAS_MODE: 0 none, 1 bias[row], 2 bias[col]. RESID adds resid[row*N+col].
// ---------------------------------------------------------------------------
template <int OUTF32, int BIAS_MODE, int RESID>
__global__ __launch_bounds__(256)
void gemm_bt(const bf16_t* __restrict__ A, const bf16_t* __restrict__ B,
             void* __restrict__ Cv, const float* __restrict__ bias,
             const float* __restrict__ resid,
             int M, int N, int K, float scale) {
  __shared__ alignas(16) bf16_t lA[4096];  // [128 rows][32 k], unpadded
  __shared__ alignas(16) bf16_t lB[4096];

  const int t = threadIdx.x;
  const int lane = t & 63;
  const int w = t >> 6;
  const int wm = (w >> 1) * 64;
  const int wn = (w & 1) * 64;
  const int bm = blockIdx.y * 128;
  const int bn = blockIdx.x * 128;

  const int lrow = lane >> 2;       // 0..15 : row within 16-row chunk
  const int lcol = (lane & 3) * 8;  // 0,8,16,24 : k element offset
  const int quad = lane >> 4;
  const int l15 = lane & 15;

  const bf16_t* gA0 = A + (size_t)(bm + w * 16 + lrow) * K + lcol;
  const bf16_t* gA1 = A + (size_t)(bm + (w + 4) * 16 + lrow) * K + lcol;
  const bf16_t* gB0 = B + (size_t)(bn + w * 16 + lrow) * K + lcol;
  const bf16_t* gB1 = B + (size_t)(bn + (w + 4) * 16 + lrow) * K + lcol;
  bf16_t* lA0 = &lA[w * 512];
  bf16_t* lA1 = &lA[(w + 4) * 512];
  bf16_t* lB0 = &lB[w * 512];
  bf16_t* lB1 = &lB[(w + 4) * 512];

  f32x4 acc[4][4] = {};

  for (int k0 = 0; k0 < K; k0 += 32) {
    __syncthreads();  // previous iter done reading LDS
    async16(gA0 + k0, lA0);
    async16(gA1 + k0, lA1);
    async16(gB0 + k0, lB0);
    async16(gB1 + k0, lB1);
    __syncthreads();  // waitcnt drain before barrier -> staged data visible

    bf16x8 af[4], bfr[4];
    #pragma unroll
    for (int i = 0; i < 4; i++) {
      af[i]  = *(const bf16x8*)&lA[(wm + i * 16 + l15) * 32 + quad * 8];
      bfr[i] = *(const bf16x8*)&lB[(wn + i * 16 + l15) * 32 + quad * 8];
    }
    #pragma unroll
    for (int i = 0; i < 4; i++)
      #pragma unroll
      for (int j = 0; j < 4; j++)
        acc[i][j] = __builtin_amdgcn_mfma_f32_16x16x32_bf16(af[i], bfr[j],
                                                            acc[i][j], 0, 0, 0);
  }

  float* Cf = (float*)Cv;
  bf16_t* Cb = (bf16_t*)Cv;

  #pragma unroll
  for (int i = 0; i < 4; i++) {
    const int row0 = bm + wm + i * 16 + quad * 4;
    #pragma unroll
    for (int j = 0; j < 4; j++) {
      const int col = bn + wn + j * 16 + l15;
      #pragma unroll
      for (int r = 0; r < 4; r++) {
        float v = acc[i][j][r] * scale;
        const int row = row0 + r;
        if (BIAS_MODE == 1) v += bias[row];
        else if (BIAS_MODE == 2) v += bias[col];
        const size_t idx = (size_t)row * N + col;
        if (RESID) v += resid[idx];
        if (OUTF32) Cf[idx] = v;
        else Cb[idx] = (bf16_t)v;
      }
    }
  }
}

// ---------------------------------------------------------------------------
// kernel_launch — batch-serial, compact workspace (~54 MB)
// ---------------------------------------------------------------------------
extern "C" void kernel_launch(void* const* d_in, const int* in_sizes, int n_in,
                              void* d_out, int out_size, void* d_ws, size_t ws_size,
                              hipStream_t stream) {
  const float* x   = (const float*)d_in[0];
  const float* gnw = (const float*)d_in[1];
  const float* gnb = (const float*)d_in[2];
  const float* qw  = (const float*)d_in[3];
  const float* qb  = (const float*)d_in[4];
  const float* kw  = (const float*)d_in[5];
  const float* kb  = (const float*)d_in[6];
  const float* vw  = (const float*)d_in[7];
  const float* vb  = (const float*)d_in[8];
  const float* pw  = (const float*)d_in[9];
  const float* pb  = (const float*)d_in[10];
  float* out = (float*)d_out;

  char* ws = (char*)d_ws;
  size_t off = 0;
  auto alloc = [&](size_t bytes) -> void* {
    void* p = ws + off;
    off += (bytes + 255) & ~(size_t)255;
    return p;
  };

  bf16_t* wqb = (bf16_t*)alloc(512ull * 512 * 2);
  bf16_t* wkb = (bf16_t*)alloc(512ull * 512 * 2);
  bf16_t* wvb = (bf16_t*)alloc(512ull * 512 * 2);
  bf16_t* wpb = (bf16_t*)alloc(512ull * 512 * 2);
  bf16_t* hb  = (bf16_t*)alloc(4096ull * 512 * 2);   // (N,C) groupnorm out
  bf16_t* qbf = (bf16_t*)alloc(4096ull * 512 * 2);   // (N,D)
  bf16_t* kbf = (bf16_t*)alloc(4096ull * 512 * 2);   // (N,D)
  bf16_t* vbf = (bf16_t*)alloc(4096ull * 512 * 2);   // (D,N)
  bf16_t* hfb = (bf16_t*)alloc(4096ull * 512 * 2);   // (N,D) attn out
  bf16_t* SP  = (bf16_t*)alloc(4096ull * 4096 * 2);  // scores/probs in-place

  // weights -> bf16 (once per call)
  f2b<<<256, 256, 0, stream>>>(qw, wqb);
  f2b<<<256, 256, 0, stream>>>(kw, wkb);
  f2b<<<256, 256, 0, stream>>>(vw, wvb);
  f2b<<<256, 256, 0, stream>>>(pw, wpb);

  const float scale = 0.044194173824159216f;  // 512^-0.5 (ref scales by C)

  for (int bb = 0; bb < 8; ++bb) {
    const size_t xoff = (size_t)bb * 512 * 4096;

    // groupnorm -> hb (N,C)
    groupnorm_t<<<32, 256, 0, stream>>>(x, gnw, gnb, hb, bb);

    // q[n,d] = sum_c hb[n,c]*qw[d,c] + qb[d]  (bias on col=d)
    gemm_bt<0, 2, 0><<<dim3(4, 32), 256, 0, stream>>>(
        hb, wqb, qbf, qb, nullptr, 4096, 512, 512, 1.0f);
    gemm_bt<0, 2, 0><<<dim3(4, 32), 256, 0, stream>>>(
        hb, wkb, kbf, kb, nullptr, 4096, 512, 512, 1.0f);
    // v[d,n] = sum_c vw[d,c]*hb[n,c] + vb[d]  (bias on row=d)
    gemm_bt<0, 1, 0><<<dim3(32, 4), 256, 0, stream>>>(
        wvb, hb, vbf, vb, nullptr, 512, 4096, 512, 1.0f);

    // S[n,m] = scale * sum_d q[n,d]*k[m,d]  -> bf16
    gemm_bt<0, 0, 0><<<dim3(32, 32), 256, 0, stream>>>(
        qbf, kbf, SP, nullptr, nullptr, 4096, 4096, 512, scale);

    // P = softmax_rows(S) in place
    softmax_row_bf16<<<4096, 256, 0, stream>>>(SP);

    // hf[n,d] = sum_m P[n,m]*v[d,m]
    gemm_bt<0, 0, 0><<<dim3(4, 32), 256, 0, stream>>>(
        SP, vbf, hfb, nullptr, nullptr, 4096, 512, 4096, 1.0f);

    // out[c,n] = x[c,n] + pb[c] + sum_d pw[c,d]*hf[n,d]
    gemm_bt<1, 1, 1><<<dim3(32, 4), 256, 0, stream>>>(
        wpb, hfb, out + xoff, pb, x + xoff, 512, 4096, 512, 1.0f);
  }
}

// Round 3
// 862.266 us; speedup vs baseline: 2.0233x; 2.0233x over previous
//
#include <hip/hip_runtime.h>
#include <hip/hip_bf16.h>
#include <cstdint>
#include <cstddef>

typedef __bf16 bf16_t;
typedef __bf16 bf16x8 __attribute__((ext_vector_type(8)));
typedef __bf16 bf16x4 __attribute__((ext_vector_type(4)));
typedef float f32x4 __attribute__((ext_vector_type(4)));

// ---------------------------------------------------------------------------
// async global->LDS, 16B per lane. LDS dest is wave-uniform base + lane*16.
// ---------------------------------------------------------------------------
__device__ __forceinline__ void async16(const void* g, void* l) {
  __builtin_amdgcn_global_load_lds(
      (const __attribute__((address_space(1))) void*)g,
      (__attribute__((address_space(3))) void*)l,
      16, 0, 0);
}

// ---------------------------------------------------------------------------
// fp32 -> bf16 weight conversion (512x512 = 65536 float4, grid 256x256)
// ---------------------------------------------------------------------------
__global__ __launch_bounds__(256) void f2b(const float* __restrict__ in,
                                           bf16_t* __restrict__ out) {
  const int i = blockIdx.x * 256 + threadIdx.x;
  float4 v = ((const float4*)in)[i];
  bf16x4 o = { (__bf16)v.x, (__bf16)v.y, (__bf16)v.z, (__bf16)v.w };
  ((bf16x4*)out)[i] = o;
}

// ---------------------------------------------------------------------------
// GroupNorm: x (B,512,4096) fp32 -> ht (4 group batches, N, C) bf16
// (transposed so downstream GEMMs are A@B^T, K-contiguous).
// blockIdx.x = group g (32), blockIdx.y = local batch lb (4). 256 threads.
// ---------------------------------------------------------------------------
__global__ __launch_bounds__(256) void groupnorm_t(const float* __restrict__ x,
                                                   const float* __restrict__ gamma,
                                                   const float* __restrict__ beta,
                                                   bf16_t* __restrict__ ht,
                                                   int b0) {
  const int g = blockIdx.x;
  const int lb = blockIdx.y;
  const int b = b0 + lb;
  const int t = threadIdx.x;
  const float* xg = x + ((size_t)(b * 512 + g * 16)) * 4096;
  const float4* x4 = (const float4*)xg;

  float s = 0.f, ss = 0.f;
  #pragma unroll 8
  for (int i = t; i < 16384; i += 256) {
    float4 v = x4[i];
    s  += (v.x + v.y) + (v.z + v.w);
    ss += (v.x * v.x + v.y * v.y) + (v.z * v.z + v.w * v.w);
  }
  #pragma unroll
  for (int o = 32; o; o >>= 1) { s += __shfl_xor(s, o); ss += __shfl_xor(ss, o); }
  __shared__ float rs[4], rss[4];
  if ((t & 63) == 0) { rs[t >> 6] = s; rss[t >> 6] = ss; }
  __syncthreads();
  const float S  = (rs[0] + rs[1]) + (rs[2] + rs[3]);
  const float SS = (rss[0] + rss[1]) + (rss[2] + rss[3]);
  const float inv_n = 1.0f / 65536.0f;
  const float mean = S * inv_n;
  const float var  = SS * inv_n - mean * mean;
  const float rstd = rsqrtf(var + 1e-5f);

  float ga[16], be[16];
  #pragma unroll
  for (int cc = 0; cc < 16; cc++) {
    const float gm = gamma[g * 16 + cc] * rstd;
    ga[cc] = gm;
    be[cc] = beta[g * 16 + cc] - mean * gm;
  }

  bf16_t* hg = ht + (size_t)lb * 4096 * 512 + g * 16;
  for (int n = t; n < 4096; n += 256) {
    bf16_t o[16];
    #pragma unroll
    for (int cc = 0; cc < 16; cc++)
      o[cc] = (bf16_t)(xg[(size_t)cc * 4096 + n] * ga[cc] + be[cc]);
    bf16x8* dst = (bf16x8*)(hg + (size_t)n * 512);
    dst[0] = *(bf16x8*)&o[0];
    dst[1] = *(bf16x8*)&o[8];
  }
}

// ---------------------------------------------------------------------------
// In-place row softmax on 4096-wide bf16 rows (scores -> probabilities).
// blockIdx.x = row, blockIdx.y = local batch. 16 values/thread in registers.
// ---------------------------------------------------------------------------
__global__ __launch_bounds__(256) void softmax_row_bf16(bf16_t* __restrict__ SP) {
  const int row = blockIdx.x;
  const int t = threadIdx.x;
  bf16_t* base = SP + (size_t)blockIdx.y * 4096 * 4096 + (size_t)row * 4096;
  bf16x8* R = (bf16x8*)base + t * 2;

  float v[16];
  bf16x8 a = R[0], b = R[1];
  #pragma unroll
  for (int i = 0; i < 8; i++) { v[i] = (float)a[i]; v[8 + i] = (float)b[i]; }

  float m = -3.0e38f;
  #pragma unroll
  for (int i = 0; i < 16; i++) m = fmaxf(m, v[i]);
  #pragma unroll
  for (int o = 32; o; o >>= 1) m = fmaxf(m, __shfl_xor(m, o));
  __shared__ float rm[4], rsum[4];
  if ((t & 63) == 0) rm[t >> 6] = m;
  __syncthreads();
  m = fmaxf(fmaxf(rm[0], rm[1]), fmaxf(rm[2], rm[3]));

  float s = 0.f;
  #pragma unroll
  for (int i = 0; i < 16; i++) { v[i] = __expf(v[i] - m); s += v[i]; }
  #pragma unroll
  for (int o = 32; o; o >>= 1) s += __shfl_xor(s, o);
  if ((t & 63) == 0) rsum[t >> 6] = s;
  __syncthreads();
  s = (rsum[0] + rsum[1]) + (rsum[2] + rsum[3]);
  const float inv = 1.0f / s;

  #pragma unroll
  for (int i = 0; i < 8; i++) { a[i] = (__bf16)(v[i] * inv); b[i] = (__bf16)(v[8 + i] * inv); }
  R[0] = a; R[1] = b;
}

// ---------------------------------------------------------------------------
// C = A @ B^T  (A: MxK row-major, B: NxK row-major, both bf16 K-contiguous).
// m97 structure: 128x128 tile, BK=32, 4 waves x (4x4) 16x16x32 bf16 MFMA,
// global_load_lds width=16 staging (wave-uniform LDS base + lane*16).
// C/D layout (verified m89/m91): col = lane&15, row = (lane>>4)*4 + reg.
// BIAS_MODE: 0 none, 1 bias[row], 2 bias[col]. RESID adds resid[row*N+col].
// blockIdx.z = local batch; element strides sA/sB/sC/sR (0 = shared).
// ---------------------------------------------------------------------------
template <int OUTF32, int BIAS_MODE, int RESID>
__global__ __launch_bounds__(256)
void gemm_bt(const bf16_t* __restrict__ A, const bf16_t* __restrict__ B,
             void* __restrict__ Cv, const float* __restrict__ bias,
             const float* __restrict__ resid,
             int M, int N, int K, float scale,
             long sA, long sB, long sC, long sR) {
  __shared__ alignas(16) bf16_t lA[4096];  // [128 rows][32 k], unpadded
  __shared__ alignas(16) bf16_t lB[4096];

  const int t = threadIdx.x;
  const int lane = t & 63;
  const int w = t >> 6;
  const int wm = (w >> 1) * 64;
  const int wn = (w & 1) * 64;
  const int bm = blockIdx.y * 128;
  const int bn = blockIdx.x * 128;
  const size_t z = blockIdx.z;
  const bf16_t* Ab = A + z * (size_t)sA;
  const bf16_t* Bb = B + z * (size_t)sB;

  const int lrow = lane >> 2;       // 0..15 : row within 16-row chunk
  const int lcol = (lane & 3) * 8;  // 0,8,16,24 : k element offset
  const int quad = lane >> 4;
  const int l15 = lane & 15;

  const bf16_t* gA0 = Ab + (size_t)(bm + w * 16 + lrow) * K + lcol;
  const bf16_t* gA1 = Ab + (size_t)(bm + (w + 4) * 16 + lrow) * K + lcol;
  const bf16_t* gB0 = Bb + (size_t)(bn + w * 16 + lrow) * K + lcol;
  const bf16_t* gB1 = Bb + (size_t)(bn + (w + 4) * 16 + lrow) * K + lcol;
  bf16_t* lA0 = &lA[w * 512];
  bf16_t* lA1 = &lA[(w + 4) * 512];
  bf16_t* lB0 = &lB[w * 512];
  bf16_t* lB1 = &lB[(w + 4) * 512];

  f32x4 acc[4][4] = {};

  for (int k0 = 0; k0 < K; k0 += 32) {
    __syncthreads();  // previous iter done reading LDS
    async16(gA0 + k0, lA0);
    async16(gA1 + k0, lA1);
    async16(gB0 + k0, lB0);
    async16(gB1 + k0, lB1);
    __syncthreads();  // waitcnt drain before barrier -> staged data visible

    bf16x8 af[4], bfr[4];
    #pragma unroll
    for (int i = 0; i < 4; i++) {
      af[i]  = *(const bf16x8*)&lA[(wm + i * 16 + l15) * 32 + quad * 8];
      bfr[i] = *(const bf16x8*)&lB[(wn + i * 16 + l15) * 32 + quad * 8];
    }
    #pragma unroll
    for (int i = 0; i < 4; i++)
      #pragma unroll
      for (int j = 0; j < 4; j++)
        acc[i][j] = __builtin_amdgcn_mfma_f32_16x16x32_bf16(af[i], bfr[j],
                                                            acc[i][j], 0, 0, 0);
  }

  float* Cf = (float*)Cv + z * (size_t)sC;
  bf16_t* Cb = (bf16_t*)Cv + z * (size_t)sC;
  const float* Rb = RESID ? (resid + z * (size_t)sR) : nullptr;

  #pragma unroll
  for (int i = 0; i < 4; i++) {
    const int row0 = bm + wm + i * 16 + quad * 4;
    #pragma unroll
    for (int j = 0; j < 4; j++) {
      const int col = bn + wn + j * 16 + l15;
      #pragma unroll
      for (int r = 0; r < 4; r++) {
        float v = acc[i][j][r] * scale;
        const int row = row0 + r;
        if (BIAS_MODE == 1) v += bias[row];
        else if (BIAS_MODE == 2) v += bias[col];
        const size_t idx = (size_t)row * N + col;
        if (RESID) v += Rb[idx];
        if (OUTF32) Cf[idx] = v;
        else Cb[idx] = (bf16_t)v;
      }
    }
  }
}

// ---------------------------------------------------------------------------
// kernel_launch — 2 groups of 4 batches, z-batched launches (~194 MB ws)
// ---------------------------------------------------------------------------
extern "C" void kernel_launch(void* const* d_in, const int* in_sizes, int n_in,
                              void* d_out, int out_size, void* d_ws, size_t ws_size,
                              hipStream_t stream) {
  const float* x   = (const float*)d_in[0];
  const float* gnw = (const float*)d_in[1];
  const float* gnb = (const float*)d_in[2];
  const float* qw  = (const float*)d_in[3];
  const float* qb  = (const float*)d_in[4];
  const float* kw  = (const float*)d_in[5];
  const float* kb  = (const float*)d_in[6];
  const float* vw  = (const float*)d_in[7];
  const float* vb  = (const float*)d_in[8];
  const float* pw  = (const float*)d_in[9];
  const float* pb  = (const float*)d_in[10];
  float* out = (float*)d_out;

  char* ws = (char*)d_ws;
  size_t off = 0;
  auto alloc = [&](size_t bytes) -> void* {
    void* p = ws + off;
    off += (bytes + 255) & ~(size_t)255;
    return p;
  };

  const long sND  = 4096L * 512;    // (N,D)/(D,N) per-batch elems
  const long sNN  = 4096L * 4096;   // (N,N) per-batch elems

  bf16_t* wqb = (bf16_t*)alloc(512ull * 512 * 2);
  bf16_t* wkb = (bf16_t*)alloc(512ull * 512 * 2);
  bf16_t* wvb = (bf16_t*)alloc(512ull * 512 * 2);
  bf16_t* wpb = (bf16_t*)alloc(512ull * 512 * 2);
  bf16_t* ht  = (bf16_t*)alloc(4ull * 4096 * 512 * 2);   // (4,N,C); aliased by hf
  bf16_t* qbf = (bf16_t*)alloc(4ull * 4096 * 512 * 2);   // (4,N,D)
  bf16_t* kbf = (bf16_t*)alloc(4ull * 4096 * 512 * 2);   // (4,N,D)
  bf16_t* vbf = (bf16_t*)alloc(4ull * 4096 * 512 * 2);   // (4,D,N)
  bf16_t* SP  = (bf16_t*)alloc(4ull * 4096 * 4096 * 2);  // (4,N,N) in-place
  bf16_t* hfb = ht;  // alias: ht dead after q/k/v GEMMs

  // weights -> bf16 (once per call)
  f2b<<<256, 256, 0, stream>>>(qw, wqb);
  f2b<<<256, 256, 0, stream>>>(kw, wkb);
  f2b<<<256, 256, 0, stream>>>(vw, wvb);
  f2b<<<256, 256, 0, stream>>>(pw, wpb);

  const float scale = 0.044194173824159216f;  // 512^-0.5 (ref scales by C)

  for (int b0 = 0; b0 < 8; b0 += 4) {
    const size_t xoff = (size_t)b0 * 512 * 4096;

    // groupnorm -> ht (lb, N, C)
    groupnorm_t<<<dim3(32, 4), 256, 0, stream>>>(x, gnw, gnb, ht, b0);

    // q[n,d] = sum_c ht[n,c]*qw[d,c] + qb[d]  (bias on col=d)
    gemm_bt<0, 2, 0><<<dim3(4, 32, 4), 256, 0, stream>>>(
        ht, wqb, qbf, qb, nullptr, 4096, 512, 512, 1.0f, sND, 0, sND, 0);
    gemm_bt<0, 2, 0><<<dim3(4, 32, 4), 256, 0, stream>>>(
        ht, wkb, kbf, kb, nullptr, 4096, 512, 512, 1.0f, sND, 0, sND, 0);
    // v[d,n] = sum_c vw[d,c]*ht[n,c] + vb[d]  (bias on row=d)
    gemm_bt<0, 1, 0><<<dim3(32, 4, 4), 256, 0, stream>>>(
        wvb, ht, vbf, vb, nullptr, 512, 4096, 512, 1.0f, 0, sND, sND, 0);

    // S[n,m] = scale * sum_d q[n,d]*k[m,d]  -> bf16
    gemm_bt<0, 0, 0><<<dim3(32, 32, 4), 256, 0, stream>>>(
        qbf, kbf, SP, nullptr, nullptr, 4096, 4096, 512, scale, sND, sND, sNN, 0);

    // P = softmax_rows(S) in place
    softmax_row_bf16<<<dim3(4096, 4), 256, 0, stream>>>(SP);

    // hf[n,d] = sum_m P[n,m]*v[d,m]   (overwrites ht)
    gemm_bt<0, 0, 0><<<dim3(4, 32, 4), 256, 0, stream>>>(
        SP, vbf, hfb, nullptr, nullptr, 4096, 512, 4096, 1.0f, sNN, sND, sND, 0);

    // out[c,n] = x[c,n] + pb[c] + sum_d pw[c,d]*hf[n,d]
    gemm_bt<1, 1, 1><<<dim3(32, 4, 4), 256, 0, stream>>>(
        wpb, hfb, out + xoff, pb, x + xoff, 512, 4096, 512, 1.0f, 0, sND, sND, sND);
  }
}

// Round 4
// 819.571 us; speedup vs baseline: 2.1287x; 1.0521x over previous
//
#include <hip/hip_runtime.h>
#include <hip/hip_bf16.h>
#include <cstdint>
#include <cstddef>

typedef __bf16 bf16_t;
typedef __bf16 bf16x8 __attribute__((ext_vector_type(8)));
typedef __bf16 bf16x4 __attribute__((ext_vector_type(4)));
typedef float f32x4 __attribute__((ext_vector_type(4)));

// ---------------------------------------------------------------------------
// async global->LDS, 16B per lane. LDS dest is wave-uniform base + lane*16.
// ---------------------------------------------------------------------------
__device__ __forceinline__ void async16(const void* g, void* l) {
  __builtin_amdgcn_global_load_lds(
      (const __attribute__((address_space(1))) void*)g,
      (__attribute__((address_space(3))) void*)l,
      16, 0, 0);
}

// ---------------------------------------------------------------------------
// fp32 -> bf16 weight conversion, 4 weight matrices in one launch.
// blockIdx.y selects the matrix; 512x512 = 65536 float4 per matrix.
// ---------------------------------------------------------------------------
__global__ __launch_bounds__(256) void f2b4(const float* __restrict__ w0,
                                            const float* __restrict__ w1,
                                            const float* __restrict__ w2,
                                            const float* __restrict__ w3,
                                            bf16_t* __restrict__ o0,
                                            bf16_t* __restrict__ o1,
                                            bf16_t* __restrict__ o2,
                                            bf16_t* __restrict__ o3) {
  const float* in = (blockIdx.y == 0) ? w0 : (blockIdx.y == 1) ? w1
                   : (blockIdx.y == 2) ? w2 : w3;
  bf16_t* out = (blockIdx.y == 0) ? o0 : (blockIdx.y == 1) ? o1
               : (blockIdx.y == 2) ? o2 : o3;
  const int i = blockIdx.x * 256 + threadIdx.x;
  float4 v = ((const float4*)in)[i];
  bf16x4 o = { (__bf16)v.x, (__bf16)v.y, (__bf16)v.z, (__bf16)v.w };
  ((bf16x4*)out)[i] = o;
}

// ---------------------------------------------------------------------------
// GroupNorm: x (B,512,4096) fp32 -> ht (4 group batches, N, C) bf16
// (transposed so downstream GEMMs are A@B^T, K-contiguous).
// blockIdx.x = group g (32), blockIdx.y = local batch lb (4). 256 threads.
// ---------------------------------------------------------------------------
__global__ __launch_bounds__(256) void groupnorm_t(const float* __restrict__ x,
                                                   const float* __restrict__ gamma,
                                                   const float* __restrict__ beta,
                                                   bf16_t* __restrict__ ht,
                                                   int b0) {
  const int g = blockIdx.x;
  const int lb = blockIdx.y;
  const int b = b0 + lb;
  const int t = threadIdx.x;
  const float* xg = x + ((size_t)(b * 512 + g * 16)) * 4096;
  const float4* x4 = (const float4*)xg;

  float s = 0.f, ss = 0.f;
  #pragma unroll 8
  for (int i = t; i < 16384; i += 256) {
    float4 v = x4[i];
    s  += (v.x + v.y) + (v.z + v.w);
    ss += (v.x * v.x + v.y * v.y) + (v.z * v.z + v.w * v.w);
  }
  #pragma unroll
  for (int o = 32; o; o >>= 1) { s += __shfl_xor(s, o); ss += __shfl_xor(ss, o); }
  __shared__ float rs[4], rss[4];
  if ((t & 63) == 0) { rs[t >> 6] = s; rss[t >> 6] = ss; }
  __syncthreads();
  const float S  = (rs[0] + rs[1]) + (rs[2] + rs[3]);
  const float SS = (rss[0] + rss[1]) + (rss[2] + rss[3]);
  const float inv_n = 1.0f / 65536.0f;
  const float mean = S * inv_n;
  const float var  = SS * inv_n - mean * mean;
  const float rstd = rsqrtf(var + 1e-5f);

  float ga[16], be[16];
  #pragma unroll
  for (int cc = 0; cc < 16; cc++) {
    const float gm = gamma[g * 16 + cc] * rstd;
    ga[cc] = gm;
    be[cc] = beta[g * 16 + cc] - mean * gm;
  }

  bf16_t* hg = ht + (size_t)lb * 4096 * 512 + g * 16;
  for (int n = t; n < 4096; n += 256) {
    bf16_t o[16];
    #pragma unroll
    for (int cc = 0; cc < 16; cc++)
      o[cc] = (bf16_t)(xg[(size_t)cc * 4096 + n] * ga[cc] + be[cc]);
    bf16x8* dst = (bf16x8*)(hg + (size_t)n * 512);
    dst[0] = *(bf16x8*)&o[0];
    dst[1] = *(bf16x8*)&o[8];
  }
}

// ---------------------------------------------------------------------------
// In-place row softmax on 4096-wide bf16 rows (scores -> probabilities).
// blockIdx.x = row, blockIdx.y = local batch. 16 values/thread in registers.
// ---------------------------------------------------------------------------
__global__ __launch_bounds__(256) void softmax_row_bf16(bf16_t* __restrict__ SP) {
  const int row = blockIdx.x;
  const int t = threadIdx.x;
  bf16_t* base = SP + (size_t)blockIdx.y * 4096 * 4096 + (size_t)row * 4096;
  bf16x8* R = (bf16x8*)base + t * 2;

  float v[16];
  bf16x8 a = R[0], b = R[1];
  #pragma unroll
  for (int i = 0; i < 8; i++) { v[i] = (float)a[i]; v[8 + i] = (float)b[i]; }

  float m = -3.0e38f;
  #pragma unroll
  for (int i = 0; i < 16; i++) m = fmaxf(m, v[i]);
  #pragma unroll
  for (int o = 32; o; o >>= 1) m = fmaxf(m, __shfl_xor(m, o));
  __shared__ float rm[4], rsum[4];
  if ((t & 63) == 0) rm[t >> 6] = m;
  __syncthreads();
  m = fmaxf(fmaxf(rm[0], rm[1]), fmaxf(rm[2], rm[3]));

  float s = 0.f;
  #pragma unroll
  for (int i = 0; i < 16; i++) { v[i] = __expf(v[i] - m); s += v[i]; }
  #pragma unroll
  for (int o = 32; o; o >>= 1) s += __shfl_xor(s, o);
  if ((t & 63) == 0) rsum[t >> 6] = s;
  __syncthreads();
  s = (rsum[0] + rsum[1]) + (rsum[2] + rsum[3]);
  const float inv = 1.0f / s;

  #pragma unroll
  for (int i = 0; i < 8; i++) { a[i] = (__bf16)(v[i] * inv); b[i] = (__bf16)(v[8 + i] * inv); }
  R[0] = a; R[1] = b;
}

// ---------------------------------------------------------------------------
// C = A @ B^T  (A: MxK row-major, B: NxK row-major, both bf16 K-contiguous).
// m97 structure: 128x128 tile, BK=32, 4 waves x (4x4) 16x16x32 bf16 MFMA,
// global_load_lds width=16 staging. C/D layout: col=lane&15, row=quad*4+reg.
//
// Flat-grid XCD-aware swizzle: xcd = lid%8 (HW round-robin heuristic).
// The tile dimension whose strips dominate fetch traffic (M side, or N side
// when SWAP=1) is grouped so all blocks sharing one strip land on the SAME
// XCD, adjacent in its slot order -> strip fetched once per XCD, L2-served.
// Requires ((SWAP?TN:TM)*Z) % 8 == 0.
// BIAS_MODE: 0 none, 1 bias[row], 2 bias[col]. RESID adds resid.
// ---------------------------------------------------------------------------
template <int OUTF32, int BIAS_MODE, int RESID, int SWAP>
__global__ __launch_bounds__(256)
void gemm_bt(const bf16_t* __restrict__ A, const bf16_t* __restrict__ B,
             void* __restrict__ Cv, const float* __restrict__ bias,
             const float* __restrict__ resid,
             int TM, int TN, int Z, int K, float scale,
             long sA, long sB, long sC, long sR) {
  __shared__ alignas(16) bf16_t lA[4096];  // [128 rows][32 k], unpadded
  __shared__ alignas(16) bf16_t lB[4096];

  // ---- swizzled tile mapping ----
  const int lid = blockIdx.x;
  const int xcd = lid & 7;
  const int j   = lid >> 3;
  const int sd  = SWAP ? TN : TM;        // strip-dim tile count (per z)
  const int I   = SWAP ? TM : TN;        // inner tile count
  const int spx = (sd * Z) >> 3;         // strips per XCD
  const int strip = xcd * spx + j / I;
  const int inner = j % I;
  const int z    = strip / sd;
  const int sidx = strip % sd;
  const int bm = (SWAP ? inner : sidx) * 128;
  const int bn = (SWAP ? sidx : inner) * 128;
  const int N = TN * 128;

  const int t = threadIdx.x;
  const int lane = t & 63;
  const int w = t >> 6;
  const int wm = (w >> 1) * 64;
  const int wn = (w & 1) * 64;
  const bf16_t* Ab = A + (size_t)z * (size_t)sA;
  const bf16_t* Bb = B + (size_t)z * (size_t)sB;

  const int lrow = lane >> 2;       // 0..15 : row within 16-row chunk
  const int lcol = (lane & 3) * 8;  // 0,8,16,24 : k element offset
  const int quad = lane >> 4;
  const int l15 = lane & 15;

  const bf16_t* gA0 = Ab + (size_t)(bm + w * 16 + lrow) * K + lcol;
  const bf16_t* gA1 = Ab + (size_t)(bm + (w + 4) * 16 + lrow) * K + lcol;
  const bf16_t* gB0 = Bb + (size_t)(bn + w * 16 + lrow) * K + lcol;
  const bf16_t* gB1 = Bb + (size_t)(bn + (w + 4) * 16 + lrow) * K + lcol;
  bf16_t* lA0 = &lA[w * 512];
  bf16_t* lA1 = &lA[(w + 4) * 512];
  bf16_t* lB0 = &lB[w * 512];
  bf16_t* lB1 = &lB[(w + 4) * 512];

  f32x4 acc[4][4] = {};

  for (int k0 = 0; k0 < K; k0 += 32) {
    __syncthreads();  // previous iter done reading LDS
    async16(gA0 + k0, lA0);
    async16(gA1 + k0, lA1);
    async16(gB0 + k0, lB0);
    async16(gB1 + k0, lB1);
    __syncthreads();  // waitcnt drain before barrier -> staged data visible

    bf16x8 af[4], bfr[4];
    #pragma unroll
    for (int i = 0; i < 4; i++) {
      af[i]  = *(const bf16x8*)&lA[(wm + i * 16 + l15) * 32 + quad * 8];
      bfr[i] = *(const bf16x8*)&lB[(wn + i * 16 + l15) * 32 + quad * 8];
    }
    #pragma unroll
    for (int i = 0; i < 4; i++)
      #pragma unroll
      for (int jj = 0; jj < 4; jj++)
        acc[i][jj] = __builtin_amdgcn_mfma_f32_16x16x32_bf16(af[i], bfr[jj],
                                                             acc[i][jj], 0, 0, 0);
  }

  float* Cf = (float*)Cv + (size_t)z * (size_t)sC;
  bf16_t* Cb = (bf16_t*)Cv + (size_t)z * (size_t)sC;
  const float* Rb = RESID ? (resid + (size_t)z * (size_t)sR) : nullptr;

  #pragma unroll
  for (int i = 0; i < 4; i++) {
    const int row0 = bm + wm + i * 16 + quad * 4;
    #pragma unroll
    for (int jj = 0; jj < 4; jj++) {
      const int col = bn + wn + jj * 16 + l15;
      #pragma unroll
      for (int r = 0; r < 4; r++) {
        float v = acc[i][jj][r] * scale;
        const int row = row0 + r;
        if (BIAS_MODE == 1) v += bias[row];
        else if (BIAS_MODE == 2) v += bias[col];
        const size_t idx = (size_t)row * N + col;
        if (RESID) v += Rb[idx];
        if (OUTF32) Cf[idx] = v;
        else Cb[idx] = (bf16_t)v;
      }
    }
  }
}

// ---------------------------------------------------------------------------
// kernel_launch — 2 groups of 4 batches, z-batched swizzled launches
// ---------------------------------------------------------------------------
extern "C" void kernel_launch(void* const* d_in, const int* in_sizes, int n_in,
                              void* d_out, int out_size, void* d_ws, size_t ws_size,
                              hipStream_t stream) {
  const float* x   = (const float*)d_in[0];
  const float* gnw = (const float*)d_in[1];
  const float* gnb = (const float*)d_in[2];
  const float* qw  = (const float*)d_in[3];
  const float* qb  = (const float*)d_in[4];
  const float* kw  = (const float*)d_in[5];
  const float* kb  = (const float*)d_in[6];
  const float* vw  = (const float*)d_in[7];
  const float* vb  = (const float*)d_in[8];
  const float* pw  = (const float*)d_in[9];
  const float* pb  = (const float*)d_in[10];
  float* out = (float*)d_out;

  char* ws = (char*)d_ws;
  size_t off = 0;
  auto alloc = [&](size_t bytes) -> void* {
    void* p = ws + off;
    off += (bytes + 255) & ~(size_t)255;
    return p;
  };

  const long sND  = 4096L * 512;    // (N,D)/(D,N) per-batch elems
  const long sNN  = 4096L * 4096;   // (N,N) per-batch elems

  bf16_t* wqb = (bf16_t*)alloc(512ull * 512 * 2);
  bf16_t* wkb = (bf16_t*)alloc(512ull * 512 * 2);
  bf16_t* wvb = (bf16_t*)alloc(512ull * 512 * 2);
  bf16_t* wpb = (bf16_t*)alloc(512ull * 512 * 2);
  bf16_t* ht  = (bf16_t*)alloc(4ull * 4096 * 512 * 2);   // (4,N,C); aliased by hf
  bf16_t* qbf = (bf16_t*)alloc(4ull * 4096 * 512 * 2);   // (4,N,D)
  bf16_t* kbf = (bf16_t*)alloc(4ull * 4096 * 512 * 2);   // (4,N,D)
  bf16_t* vbf = (bf16_t*)alloc(4ull * 4096 * 512 * 2);   // (4,D,N)
  bf16_t* SP  = (bf16_t*)alloc(4ull * 4096 * 4096 * 2);  // (4,N,N) in-place
  bf16_t* hfb = ht;  // alias: ht dead after q/k/v GEMMs

  // weights -> bf16 (one launch)
  f2b4<<<dim3(256, 4), 256, 0, stream>>>(qw, kw, vw, pw, wqb, wkb, wvb, wpb);

  const float scale = 0.044194173824159216f;  // 512^-0.5 (ref scales by C)

  for (int b0 = 0; b0 < 8; b0 += 4) {
    const size_t xoff = (size_t)b0 * 512 * 4096;

    // groupnorm -> ht (lb, N, C)
    groupnorm_t<<<dim3(32, 4), 256, 0, stream>>>(x, gnw, gnb, ht, b0);

    // q[n,d] = sum_c ht[n,c]*qw[d,c] + qb[d]  (bias on col=d)
    gemm_bt<0, 2, 0, 0><<<512, 256, 0, stream>>>(
        ht, wqb, qbf, qb, nullptr, 32, 4, 4, 512, 1.0f, sND, 0, sND, 0);
    gemm_bt<0, 2, 0, 0><<<512, 256, 0, stream>>>(
        ht, wkb, kbf, kb, nullptr, 32, 4, 4, 512, 1.0f, sND, 0, sND, 0);
    // v[d,n] = sum_c vw[d,c]*ht[n,c] + vb[d]  (bias on row=d; B-strips big)
    gemm_bt<0, 1, 0, 1><<<512, 256, 0, stream>>>(
        wvb, ht, vbf, vb, nullptr, 4, 32, 4, 512, 1.0f, 0, sND, sND, 0);

    // S[n,m] = scale * sum_d q[n,d]*k[m,d]  -> bf16
    gemm_bt<0, 0, 0, 0><<<4096, 256, 0, stream>>>(
        qbf, kbf, SP, nullptr, nullptr, 32, 32, 4, 512, scale, sND, sND, sNN, 0);

    // P = softmax_rows(S) in place
    softmax_row_bf16<<<dim3(4096, 4), 256, 0, stream>>>(SP);

    // hf[n,d] = sum_m P[n,m]*v[d,m]   (overwrites ht; P-strips dominate)
    gemm_bt<0, 0, 0, 0><<<512, 256, 0, stream>>>(
        SP, vbf, hfb, nullptr, nullptr, 32, 4, 4, 4096, 1.0f, sNN, sND, sND, 0);

    // out[c,n] = x[c,n] + pb[c] + sum_d pw[c,d]*hf[n,d]  (B-strips big)
    gemm_bt<1, 1, 1, 1><<<512, 256, 0, stream>>>(
        wpb, hfb, out + xoff, pb, x + xoff, 4, 32, 4, 512, 1.0f, 0, sND, sND, sND);
  }
}